// Round 5
// baseline (667.396 us; speedup 1.0000x reference)
//
#include <hip/hip_runtime.h>

#define THREADS 256
#define SCTHREADS 1024        // scatter block size
#define BSHIFT 11
#define BSIZE 2048            // neurons per sort-bucket (11-bit local id in pk)
#define NBMAX 512             // max sort-buckets (N <= 2^20 -> <= 512)
#define PASS_EDGES 8192       // edges sorted per pass (64 KB LDS stage)
#define EPT 8                 // edges per thread per pass (1024*8 = 8192)
// ---- level-2 geometry (regroup/consume) ----
#define GSH 13                // dst-group = 8192 neurons = 4 sort-buckets
#define GRP 8192
#define G 4
#define TSH 13                // src-tile = 8192 neurons (32 KB LDS stage)
#define NTILE 128             // max src tiles (N <= 2^20)
#define SLAB 8192             // edges per src-tile-sorted slab
#define NPQMAX 640            // max passes per pass-quarter (NP <= 2560)
#define NUMAX 512             // max units = dst-groups * 4 pass-quarters
// ---- path-B (round-2 consumer) params ----
#define BTHREADS 1024
#define ACCSIZE 8192
#define SPLIT 4
#define NPSMAX 640
typedef unsigned int u32;
typedef unsigned short u16;
typedef unsigned long long u64;

// ---------------- common small kernels ----------------

// v[i] = x[i] for inputs else 0 ; nxt[i] = bias-init (step-0 accumulator)
__global__ void prep_kernel(const float* __restrict__ x, const float* __restrict__ bias,
                            float* __restrict__ v, float* __restrict__ nxt,
                            int N, int IN) {
    int i = blockIdx.x * THREADS + threadIdx.x;
    if (i >= N) return;
    v[i]   = (i < IN) ? x[i] : 0.0f;
    nxt[i] = (i < IN) ? 0.0f : bias[i - IN];
}

// in-place: v = isOutput ? v : tanh(v)
__global__ void finalize0_kernel(float* __restrict__ v, int N, int OUT) {
    int i = blockIdx.x * THREADS + threadIdx.x;
    if (i >= N) return;
    float val = v[i];
    v[i] = (i >= N - OUT) ? val : tanhf(val);
}

// state = f(nxt + bias) in place; nxt holds raw accumulated sums (zero-init'd)
__global__ void finalize_fast_kernel(float* __restrict__ nxt, const float* __restrict__ bias,
                                     float* __restrict__ out,   // null except last step
                                     int N, int IN, int OUT) {
    int i = blockIdx.x * THREADS + threadIdx.x;
    if (i >= N) return;
    float val = nxt[i] + (i >= IN ? bias[i - IN] : 0.0f);
    bool isOut = (i >= N - OUT);
    float a = isOut ? val : tanhf(val);
    nxt[i] = a;
    if (out != nullptr && isOut) out[i - (N - OUT)] = a;
}

// ---------------- level-1: per-pass dst-bucket sort (unchanged, proven) ----------------

__global__ void __launch_bounds__(SCTHREADS)
scatter_kernel(const int* __restrict__ src, const int* __restrict__ dst,
               const float* __restrict__ w,
               const float* __restrict__ vA,   // step-0 input state
               float* __restrict__ vB,         // step-0 accumulator (bias-init)
               uint2* __restrict__ e8, u16* __restrict__ dir,
               int E, int IN, int NB, int NP) {
    __shared__ __align__(16) uint2 stage[PASS_EDGES];   // 64 KB
    __shared__ u32 hc[NBMAX];               // histogram, then rank counter
    __shared__ u32 runStart[NBMAX + 1];     // exclusive scan of hc

    const int tid = threadIdx.x;
    for (int i = tid; i < NBMAX; i += SCTHREADS) hc[i] = 0;
    __syncthreads();

    for (int p = blockIdx.x; p < NP; p += gridDim.x) {
        int ps = p * PASS_EDGES;
        int pe = ps + PASS_EDGES; if (pe > E) pe = E;
        int cntAll = pe - ps;

        int base = ps + tid * EPT;
        u32 pk[EPT]; u32 bk[EPT]; u32 wb[EPT];
        int cnt = 0;
        if (base + EPT <= pe) {
            int4 s0 = *(const int4*)(src + base), s1 = *(const int4*)(src + base + 4);
            int4 d0 = *(const int4*)(dst + base), d1 = *(const int4*)(dst + base + 4);
            float4 w0 = *(const float4*)(w + base), w1 = *(const float4*)(w + base + 4);
            int ss[EPT] = {s0.x, s0.y, s0.z, s0.w, s1.x, s1.y, s1.z, s1.w};
            int dd[EPT] = {d0.x, d0.y, d0.z, d0.w, d1.x, d1.y, d1.z, d1.w};
            float ww[EPT] = {w0.x, w0.y, w0.z, w0.w, w1.x, w1.y, w1.z, w1.w};
            cnt = EPT;
            #pragma unroll
            for (int i = 0; i < EPT; ++i) {
                u32 d = (u32)dd[i];
                bk[i] = d >> BSHIFT;
                pk[i] = (u32)ss[i] | ((d & (BSIZE - 1u)) << 20);
                wb[i] = __float_as_uint(ww[i]);
                if (ss[i] < IN) atomicAdd(&vB[dd[i]], vA[ss[i]] * ww[i]);
            }
        } else {
            for (int i = 0; i < EPT; ++i) {
                int e = base + i;
                if (e < pe) {
                    int s = src[e];
                    u32 d = (u32)dst[e];
                    float wv = w[e];
                    bk[cnt] = d >> BSHIFT;
                    pk[cnt] = (u32)s | ((d & (BSIZE - 1u)) << 20);
                    wb[cnt] = __float_as_uint(wv);
                    if (s < IN) atomicAdd(&vB[d], vA[s] * wv);
                    ++cnt;
                }
            }
        }

        for (int i = 0; i < cnt; ++i) atomicAdd(&hc[bk[i]], 1u);
        __syncthreads();

        if (tid < 64) {
            u32 c[8]; u32 s = 0;
            #pragma unroll
            for (int k = 0; k < 8; ++k) { c[k] = hc[tid * 8 + k]; s += c[k]; }
            u32 inc = s;
            #pragma unroll
            for (int off = 1; off < 64; off <<= 1) {
                u32 t = __shfl_up(inc, off, 64);
                if (tid >= off) inc += t;
            }
            u32 excl = inc - s;
            #pragma unroll
            for (int k = 0; k < 8; ++k) {
                runStart[tid * 8 + k] = excl;
                excl += c[k];
                hc[tid * 8 + k] = 0;           // rank counters
            }
            if (tid == 63) runStart[NBMAX] = excl;
        }
        __syncthreads();

        for (int i = 0; i < cnt; ++i) {
            u32 b = bk[i];
            u32 r = atomicAdd(&hc[b], 1u);
            stage[runStart[b] + r] = make_uint2(pk[i], wb[i]);
        }
        __syncthreads();

        for (int j = tid * 2; j + 1 < cntAll; j += SCTHREADS * 2)
            *(uint4*)(e8 + ps + j) = *(const uint4*)(stage + j);
        if ((cntAll & 1) && tid == 0) e8[ps + cntAll - 1] = stage[cntAll - 1];
        if (tid <= NB) dir[(u32)p * (u32)(NB + 1) + tid] = (u16)runStart[tid];
        if (tid < NBMAX) hc[tid] = 0;
        __syncthreads();
    }
}

// ---------------- level-2: unit metadata ----------------

// unit = (dst-group g, pass-quarter pq). mc[u] = edge count of the unit.
__global__ void unitcnt_kernel(const u16* __restrict__ dir1, u32* __restrict__ mc,
                               int NB, int NP) {
    __shared__ u32 wsum[4];
    const int tid = threadIdx.x;
    const int g = blockIdx.x >> 2, pq = blockIdx.x & 3;
    const int NPQ = (NP + 3) >> 2;
    const int p0 = pq * NPQ;
    int pc = NP - p0; if (pc > NPQ) pc = NPQ; if (pc < 0) pc = 0;
    int c0 = g * G; if (c0 > NB) c0 = NB;
    int c1 = g * G + G; if (c1 > NB) c1 = NB;
    u32 sum = 0;
    for (int p = tid; p < pc; p += 256) {
        const u16* row = dir1 + (u32)(p0 + p) * (u32)(NB + 1);
        sum += (u32)row[c1] - (u32)row[c0];
    }
    #pragma unroll
    for (int off = 32; off; off >>= 1) sum += __shfl_down(sum, off, 64);
    if ((tid & 63) == 0) wsum[tid >> 6] = sum;
    __syncthreads();
    if (tid == 0) mc[blockIdx.x] = wsum[0] + wsum[1] + wsum[2] + wsum[3];
}

// single block: mo = exclusive scan of even-padded counts (e9 offsets),
// mr = exclusive scan of slab counts (dir2 row bases)
__global__ void unitscan_kernel(const u32* __restrict__ mc, u32* __restrict__ mo,
                                u32* __restrict__ mr, int NU) {
    __shared__ u32 s[NUMAX];
    const int t = threadIdx.x;
    u32 cnt = (t < NU) ? mc[t] : 0u;
    u32 pcnt = (cnt + 1u) & ~1u;      // pad to even for 16B-aligned writes
    s[t] = pcnt;
    __syncthreads();
    for (int off = 1; off < NUMAX; off <<= 1) {
        u32 v = (t >= off) ? s[t - off] : 0u;
        __syncthreads();
        s[t] += v;
        __syncthreads();
    }
    if (t < NU) mo[t] = s[t] - pcnt;
    __syncthreads();
    u32 rows = (cnt + SLAB - 1u) >> 13;
    s[t] = rows;
    __syncthreads();
    for (int off = 1; off < NUMAX; off <<= 1) {
        u32 v = (t >= off) ? s[t - off] : 0u;
        __syncthreads();
        s[t] += v;
        __syncthreads();
    }
    if (t < NU) mr[t] = s[t] - rows;
}

// ---------------- level-2: regroup (one-time) ----------------
// Per unit: read the group's per-pass segments (via dir1), pack into 8192-edge
// slabs, counting-sort each slab by 7-bit src-tile in LDS (2-pass ingest:
// histogram from HBM, ranked placement from L2), stream out + dir2 row.
__global__ void __launch_bounds__(1024)
regroup_kernel(const uint2* __restrict__ e8, const u16* __restrict__ dir1,
               const u32* __restrict__ mo, const u32* __restrict__ mr,
               uint2* __restrict__ e9, u16* __restrict__ dir2,
               int NB, int NP) {
    __shared__ __align__(16) uint2 stg[SLAB];   // 64 KB
    __shared__ u16 sb[G + 1][NPQMAX];       // 6.4 KB dir1 columns
    __shared__ u32 gpfx[NPQMAX + 1];        // 2.6 KB exclusive pass-length prefix
    __shared__ u32 scanb[1024];             // 4 KB scan temp
    __shared__ u32 hist[NTILE];
    __shared__ u32 rs2[NTILE + 1];
    __shared__ int shr[2];

    const int tid = threadIdx.x, wv = tid >> 6, ln = tid & 63;
    const int g = blockIdx.x >> 2, pq = blockIdx.x & 3;
    const int b0 = g * G;
    const int NPQ = (NP + 3) >> 2;
    const int p0 = pq * NPQ;
    int pc = NP - p0; if (pc > NPQ) pc = NPQ; if (pc < 0) pc = 0;

    for (int idx = tid; idx < pc * (G + 1); idx += 1024) {
        int i = idx / (G + 1), k = idx - i * (G + 1);
        int col = b0 + k; if (col > NB) col = NB;
        sb[k][i] = dir1[(u32)(p0 + i) * (u32)(NB + 1) + col];
    }
    __syncthreads();
    // exclusive scan of per-pass group-segment lengths -> gpfx
    u32 own = (tid < pc) ? (u32)sb[G][tid] - (u32)sb[0][tid] : 0u;
    scanb[tid] = own;
    __syncthreads();
    for (int off = 1; off < 1024; off <<= 1) {
        u32 t = (tid >= off) ? scanb[tid - off] : 0u;
        __syncthreads();
        scanb[tid] += t;
        __syncthreads();
    }
    if (tid < pc) gpfx[tid] = scanb[tid] - own;
    if (tid == 0) gpfx[pc] = (pc > 0) ? scanb[pc - 1] : 0u;
    __syncthreads();

    const u32 cnt = gpfx[pc];
    const u32 offU = mo[blockIdx.x];
    const u32 rowB = mr[blockIdx.x];
    const int nslab = (int)((cnt + SLAB - 1u) >> 13);

    for (int q = 0; q < nslab; ++q) {
        const u32 lo = (u32)q << 13;
        u32 hi = lo + SLAB; if (hi > cnt) hi = cnt;
        if (tid == 0) {
            int pl = (q == 0) ? 0 : shr[0];
            while (pl < pc && gpfx[pl + 1] <= lo) ++pl;
            int ph = pl;
            while (ph < pc && gpfx[ph] < hi) ++ph;
            shr[0] = pl; shr[1] = ph;
        }
        if (tid < NTILE) hist[tid] = 0;
        __syncthreads();
        const int plo = shr[0], phi = shr[1];

        // ingest A: src-tile histogram (HBM read, lines land in L2)
        for (int p = plo + wv; p < phi; p += 16) {
            const u32 gp = gpfx[p], L = gpfx[p + 1] - gp;
            const u32 s0 = sb[0][p];
            const size_t eb = (size_t)(p0 + p) * PASS_EDGES + s0;
            u32 k0 = (lo > gp) ? lo - gp : 0u;
            u32 k1 = (hi < gp + L) ? hi - gp : L;
            for (u32 k = k0 + ln; k < k1; k += 64) {
                u32 pk = e8[eb + k].x;
                atomicAdd(&hist[(pk & 0xFFFFFu) >> TSH], 1u);
            }
        }
        __syncthreads();
        // scan 128 tile counts (wave 0), zero hist for ranking
        if (tid < 64) {
            u32 c0 = hist[tid * 2], c1 = hist[tid * 2 + 1];
            u32 s = c0 + c1, inc = s;
            #pragma unroll
            for (int off = 1; off < 64; off <<= 1) {
                u32 t = __shfl_up(inc, off, 64);
                if (tid >= off) inc += t;
            }
            u32 excl = inc - s;
            rs2[tid * 2] = excl;
            rs2[tid * 2 + 1] = excl + c0;
            hist[tid * 2] = 0; hist[tid * 2 + 1] = 0;
            if (tid == 63) rs2[NTILE] = inc;
        }
        __syncthreads();
        // ingest B: ranked placement (re-read, L2-hot); repack record
        for (int p = plo + wv; p < phi; p += 16) {
            const u32 gp = gpfx[p], L = gpfx[p + 1] - gp;
            const u32 s0 = sb[0][p];
            const u32 b1 = (u32)sb[1][p] - s0, b2 = (u32)sb[2][p] - s0, b3 = (u32)sb[3][p] - s0;
            const size_t eb = (size_t)(p0 + p) * PASS_EDGES + s0;
            u32 k0 = (lo > gp) ? lo - gp : 0u;
            u32 k1 = (hi < gp + L) ? hi - gp : L;
            for (u32 k = k0 + ln; k < k1; k += 64) {
                uint2 rec = e8[eb + k];
                u32 srcg = rec.x & 0xFFFFFu;
                u32 dl = rec.x >> 20;                       // 11-bit dst within bucket
                u32 r = (u32)(k >= b1) + (u32)(k >= b2) + (u32)(k >= b3);
                u32 tile = srcg >> TSH;
                u32 rk = atomicAdd(&hist[tile], 1u);
                // pk2 = srcLocal13 | dstLocal13 << 13
                stg[rs2[tile] + rk] =
                    make_uint2((srcg & (GRP - 1u)) | (((r << BSHIFT) | dl) << TSH), rec.y);
            }
        }
        __syncthreads();
        // stream slab out (nontemporal u64, coalesced) + dir2 row
        const u32 m = hi - lo;
        u64* o64 = (u64*)(e9 + (size_t)offU + ((size_t)q << 13));
        const u64* s64 = (const u64*)stg;
        for (u32 j = tid; j < m; j += 1024)
            __builtin_nontemporal_store(s64[j], o64 + j);
        if (tid <= NTILE)
            dir2[(size_t)(rowB + q) * (NTILE + 1) + tid] = (u16)rs2[tid];
        __syncthreads();
    }
}

// ---------------- level-2: consumer (per step) ----------------
// block = (dst-group g, src-quarter sq). Stages one 32 KB v-tile at a time;
// per edge: streaming e9 load + LDS v read + LDS acc atomic. No random global.
__global__ void __launch_bounds__(1024)
consume_kernel(const uint2* __restrict__ e9, const u16* __restrict__ dir2,
               const u32* __restrict__ mc, const u32* __restrict__ mo,
               const u32* __restrict__ mr,
               const float* __restrict__ v_in, float* __restrict__ nxt,
               int N) {
    __shared__ float acc[GRP];              // 32 KB
    __shared__ float vt[GRP];               // 32 KB
    __shared__ u32 uoff[4], urow[4], pfx[5];

    const int tid = threadIdx.x, wv = tid >> 6, ln = tid & 63;
    const int g = blockIdx.x >> 2, sq = blockIdx.x & 3;

    if (tid < 4) {
        int u = g * 4 + tid;
        uoff[tid] = mo[u];
        urow[tid] = mr[u];
    }
    __syncthreads();
    if (tid == 0) {
        pfx[0] = 0;
        for (int i = 0; i < 4; ++i) {
            u32 c = mc[g * 4 + i];
            pfx[i + 1] = pfx[i] + ((c + SLAB - 1u) >> 13);
        }
    }
    for (int i = tid; i < GRP; i += 1024) acc[i] = 0.0f;
    __syncthreads();
    const int tot = (int)pfx[4];

    for (int s = sq * (NTILE / 4); s < (sq + 1) * (NTILE / 4); ++s) {
        const int vb = s << TSH;
        if (vb + GRP <= N) {
            for (int j = tid; j < GRP / 4; j += 1024)
                *(float4*)&vt[j * 4] = *(const float4*)(v_in + vb + j * 4);
        } else {
            for (int j = tid; j < GRP; j += 1024) {
                int idx = vb + j;
                vt[j] = (idx < N) ? v_in[idx] : 0.0f;
            }
        }
        __syncthreads();
        for (int pr = wv; pr < tot; pr += 16) {
            int u = 0;
            while (pr >= (int)pfx[u + 1]) ++u;
            const int q = pr - (int)pfx[u];
            const u16* row = dir2 + (size_t)(urow[u] + q) * (NTILE + 1) + s;
            const u32 a = row[0], b = row[1];
            const uint2* base = e9 + (size_t)uoff[u] + ((size_t)q << 13);
            for (u32 j = a + ln; j < b; j += 64) {
                u64 pv = __builtin_nontemporal_load((const u64*)(base + j));
                u32 px = (u32)pv;
                float pw = __uint_as_float((u32)(pv >> 32));
                atomicAdd(&acc[px >> TSH], vt[px & (GRP - 1u)] * pw);
            }
        }
        __syncthreads();   // vt overwritten next tile
    }
    const int nb = g << GSH;
    for (int j = tid; j < GRP; j += 1024) {
        int idx = nb + j;
        if (idx < N) atomicAdd(&nxt[idx], acc[j]);
    }
}

// ---------------- path B: round-2 consumer (ws-limited) ----------------

__global__ void __launch_bounds__(BTHREADS)
bucket_step_kernel(const uint2* __restrict__ e8, const u16* __restrict__ dir,
                   const float* __restrict__ v_in, float* __restrict__ nxt,
                   int N, int NB, int NP) {
    __shared__ float acc[ACCSIZE];
    __shared__ u16 sb[G + 1][NPSMAX];
    const int tid = threadIdx.x;
    const int gb = blockIdx.x >> 2;
    const int sp = blockIdx.x & 3;

    const int NPS = (NP + SPLIT - 1) / SPLIT;
    const int p0 = sp * NPS;
    int pc = NP - p0; if (pc > NPS) pc = NPS; if (pc < 0) pc = 0;

    const int b0 = gb << 2;
    for (int idx = tid; idx < pc * (G + 1); idx += BTHREADS) {
        int i = idx / (G + 1), k = idx - i * (G + 1);
        int col = b0 + k; if (col > NB) col = NB;
        sb[k][i] = dir[(u32)(p0 + i) * (u32)(NB + 1) + col];
    }
    for (int i = tid; i < ACCSIZE; i += BTHREADS) acc[i] = 0.0f;
    __syncthreads();

    const int wv = tid >> 6, ln = tid & 63;
    for (int pp = wv; pp < pc; pp += 64) {
        int  jj[4], je[4], eb[4];
        u32  s1[4], s2[4], s3[4];
        bool act[4];
        #pragma unroll
        for (int c = 0; c < 4; ++c) {
            int i = pp + c * 16;
            act[c] = false;
            if (i < pc) {
                u32 a0 = sb[0][i];
                s1[c] = sb[1][i]; s2[c] = sb[2][i]; s3[c] = sb[3][i];
                jj[c] = (int)a0 + ln;
                je[c] = (int)sb[4][i];
                eb[c] = (p0 + i) * PASS_EDGES;
                act[c] = jj[c] < je[c];
            }
        }
        while (act[0] | act[1] | act[2] | act[3]) {
            u64 pv[4];
            #pragma unroll
            for (int c = 0; c < 4; ++c)
                if (act[c]) pv[c] = __builtin_nontemporal_load((const u64*)(e8 + eb[c] + jj[c]));
            float vv[4];
            #pragma unroll
            for (int c = 0; c < 4; ++c)
                if (act[c]) vv[c] = v_in[(u32)pv[c] & 0xFFFFFu];
            #pragma unroll
            for (int c = 0; c < 4; ++c) {
                if (act[c]) {
                    u32 px = (u32)pv[c];
                    u32 j  = (u32)jj[c];
                    u32 r  = (u32)(j >= s1[c]) + (u32)(j >= s2[c]) + (u32)(j >= s3[c]);
                    float pw = __uint_as_float((u32)(pv[c] >> 32));
                    atomicAdd(&acc[(r << BSHIFT) + (px >> 20)], vv[c] * pw);
                    jj[c] += 64;
                    act[c] = jj[c] < je[c];
                }
            }
        }
    }
    __syncthreads();

    int nbase = b0 << BSHIFT;
    for (int j = tid; j < ACCSIZE; j += BTHREADS) {
        int idx = nbase + j;
        if (idx < N) atomicAdd(&nxt[idx], acc[j]);
    }
}

// ---------------- fallback path (atomic version) ----------------

__global__ void edge_kernel(const int* __restrict__ src, const int* __restrict__ dst,
                            const float* __restrict__ w, const float* __restrict__ v,
                            float* __restrict__ nxt, int E) {
    int k = blockIdx.x * THREADS + threadIdx.x;
    int E4 = E >> 2;
    if (k < E4) {
        int4 s = ((const int4*)src)[k];
        int4 d = ((const int4*)dst)[k];
        float4 wv = ((const float4*)w)[k];
        atomicAdd(&nxt[d.x], v[s.x] * wv.x);
        atomicAdd(&nxt[d.y], v[s.y] * wv.y);
        atomicAdd(&nxt[d.z], v[s.z] * wv.z);
        atomicAdd(&nxt[d.w], v[s.w] * wv.w);
    }
    if (k == 0) {
        for (int e = E4 << 2; e < E; ++e)
            atomicAdd(&nxt[dst[e]], v[src[e]] * w[e]);
    }
}

__global__ void finalize_kernel(float* __restrict__ nxt, float* __restrict__ v,
                                const float* __restrict__ bias, float* __restrict__ out,
                                int N, int IN, int OUT) {
    int i = blockIdx.x * THREADS + threadIdx.x;
    if (i >= N) return;
    float val = nxt[i];
    bool isOut = (i >= N - OUT);
    float a = isOut ? val : tanhf(val);
    v[i] = a;
    nxt[i] = (i < IN) ? 0.0f : bias[i - IN];
    if (out != nullptr && isOut) out[i - (N - OUT)] = a;
}

// ---------------- launch ----------------

extern "C" void kernel_launch(void* const* d_in, const int* in_sizes, int n_in,
                              void* d_out, int out_size, void* d_ws, size_t ws_size,
                              hipStream_t stream) {
    const float* x    = (const float*)d_in[0];
    const float* w    = (const float*)d_in[1];
    const float* bias = (const float*)d_in[2];
    const int* src = (const int*)d_in[3];
    const int* dst = (const int*)d_in[4];

    const int IN  = in_sizes[0];
    const int E   = in_sizes[1];
    const int N   = IN + in_sizes[2];
    const int OUT = out_size;

    const int NP = (E + PASS_EDGES - 1) / PASS_EDGES;
    const int NB = (N + BSIZE - 1) >> BSHIFT;
    const int NG = (N + GRP - 1) >> GSH;
    const int NU = NG * 4;
    const int ROWB = NP + NUMAX + 8;

    int nBlocks = (N + THREADS - 1) / THREADS;

    // ---- path-A workspace layout ----
    uint2* e8   = (uint2*)d_ws;                                          // E
    size_t off  = (size_t)E * 8;
    u16*   dir1 = (u16*)((char*)d_ws + off);                             // NP*(NB+1)
    off += ((size_t)NP * (NB + 1) * 2 + 15) & ~(size_t)15;
    uint2* e9   = (uint2*)((char*)d_ws + off);                           // E + NUMAX
    off += (size_t)(E + NUMAX) * 8;
    u16*   dir2 = (u16*)((char*)d_ws + off);                             // ROWB*(NTILE+1)
    off += ((size_t)ROWB * (NTILE + 1) * 2 + 15) & ~(size_t)15;
    u32*   mc   = (u32*)((char*)d_ws + off);
    u32*   mo   = mc + NUMAX;
    u32*   mr   = mo + NUMAX;
    off += (size_t)NUMAX * 3 * 4;
    off = (off + 15) & ~(size_t)15;
    float* vA   = (float*)((char*)d_ws + off);
    float* vB   = vA + N;
    size_t needA = off + (size_t)N * 8;

    // ---- path-B workspace layout (round 2) ----
    u16*   dir1B = (u16*)(e8 + E);
    size_t dirB  = (size_t)NP * (NB + 1) * 2;
    float* vAB   = (float*)((char*)dir1B + ((dirB + 15) & ~(size_t)15));
    float* vBB   = vAB + N;
    size_t needB = (size_t)((char*)(vBB + N) - (char*)d_ws);

    if (ws_size >= needA && N <= (NBMAX << BSHIFT) && NP <= 4 * NPQMAX && NU <= NUMAX) {
        prep_kernel<<<nBlocks, THREADS, 0, stream>>>(x, bias, vA, vB, N, IN);
        scatter_kernel<<<512, SCTHREADS, 0, stream>>>(
            src, dst, w, vA, vB, e8, dir1, E, IN, NB, NP);
        finalize0_kernel<<<nBlocks, THREADS, 0, stream>>>(vB, N, OUT);   // vB = state S1
        // one-time regroup into (dst-group, src-tile) slabs
        unitcnt_kernel<<<NU, 256, 0, stream>>>(dir1, mc, NB, NP);
        unitscan_kernel<<<1, NUMAX, 0, stream>>>(mc, mo, mr, NU);
        regroup_kernel<<<NU, 1024, 0, stream>>>(e8, dir1, mo, mr, e9, dir2, NB, NP);
        // step 1
        hipMemsetAsync(vA, 0, (size_t)N * sizeof(float), stream);
        consume_kernel<<<NU, 1024, 0, stream>>>(e9, dir2, mc, mo, mr, vB, vA, N);
        finalize_fast_kernel<<<nBlocks, THREADS, 0, stream>>>(vA, bias, nullptr, N, IN, OUT);
        // step 2
        hipMemsetAsync(vB, 0, (size_t)N * sizeof(float), stream);
        consume_kernel<<<NU, 1024, 0, stream>>>(e9, dir2, mc, mo, mr, vA, vB, N);
        finalize_fast_kernel<<<nBlocks, THREADS, 0, stream>>>(vB, bias, (float*)d_out, N, IN, OUT);
    } else if (ws_size >= needB && N <= (NBMAX << BSHIFT) && NP <= SPLIT * NPSMAX) {
        const int NBG = ((NB + G - 1) >> 2);
        prep_kernel<<<nBlocks, THREADS, 0, stream>>>(x, bias, vAB, vBB, N, IN);
        scatter_kernel<<<512, SCTHREADS, 0, stream>>>(
            src, dst, w, vAB, vBB, e8, dir1B, E, IN, NB, NP);
        finalize0_kernel<<<nBlocks, THREADS, 0, stream>>>(vBB, N, OUT);
        hipMemsetAsync(vAB, 0, (size_t)N * sizeof(float), stream);
        bucket_step_kernel<<<NBG * SPLIT, BTHREADS, 0, stream>>>(
            e8, dir1B, vBB, vAB, N, NB, NP);
        finalize_fast_kernel<<<nBlocks, THREADS, 0, stream>>>(vAB, bias, nullptr, N, IN, OUT);
        hipMemsetAsync(vBB, 0, (size_t)N * sizeof(float), stream);
        bucket_step_kernel<<<NBG * SPLIT, BTHREADS, 0, stream>>>(
            e8, dir1B, vAB, vBB, N, NB, NP);
        finalize_fast_kernel<<<nBlocks, THREADS, 0, stream>>>(vBB, bias, (float*)d_out, N, IN, OUT);
    } else {
        float* v   = (float*)d_ws;
        float* nxt = v + N;
        int eBlocks = ((E >> 2) + THREADS - 1) / THREADS;
        prep_kernel<<<nBlocks, THREADS, 0, stream>>>(x, bias, v, nxt, N, IN);
        for (int step = 0; step < 3; ++step) {
            edge_kernel<<<eBlocks, THREADS, 0, stream>>>(src, dst, w, v, nxt, E);
            float* outp = (step == 2) ? (float*)d_out : nullptr;
            finalize_kernel<<<nBlocks, THREADS, 0, stream>>>(nxt, v, bias, outp, N, IN, OUT);
        }
    }
}